// Round 4
// baseline (365.060 us; speedup 1.0000x reference)
//
#include <hip/hip_runtime.h>

#define Bq 128
#define Sq 512
#define Cq 37
#define Dq 768
#define VST 40   // vhist row stride in floats; bp row stride uses Sq

static __device__ __forceinline__ float frl(float v, int lane) {
  return __int_as_float(__builtin_amdgcn_readlane(__float_as_int(v), lane));
}
static __device__ __forceinline__ float ffl(float v) {
  return __int_as_float(__builtin_amdgcn_readfirstlane(__float_as_int(v)));
}

// Repeat a macro for i = 0..36 (pasted literals -> all indices compile-time).
// Named scalars are SSA values: the compiler CANNOT demote them to scratch,
// unlike float arr[37] (R3: VGPR_Count=36 proved Ecol/Tcol lived in scratch,
// 967 cyc/step).
#define REP37(X) X(0)X(1)X(2)X(3)X(4)X(5)X(6)X(7)X(8)X(9)X(10)X(11)X(12)X(13) \
  X(14)X(15)X(16)X(17)X(18)X(19)X(20)X(21)X(22)X(23)X(24)X(25)X(26)X(27)X(28) \
  X(29)X(30)X(31)X(32)X(33)X(34)X(35)X(36)

// ---------------- Kernel 0: transpose W -> Wt[c][d] ----------------
__global__ __launch_bounds__(256) void prep_kernel(
    const float* __restrict__ W, float* __restrict__ Wt)
{
  for (int i = blockIdx.x * 256 + threadIdx.x; i < Dq * Cq; i += gridDim.x * 256) {
    int d = i / Cq, c = i % Cq;
    Wt[(size_t)c * Dq + d] = W[i];
  }
}

// ---------------- Kernel 1: emissions = x @ W + b ----------------
__global__ __launch_bounds__(256) void emis_kernel(
    const float* __restrict__ x, const float* __restrict__ Wt,
    const float* __restrict__ bias, float* __restrict__ em)
{
  __shared__ float tile[64 * 36];
  int tid = threadIdx.x;
  int lane = tid & 63;
  int wq = __builtin_amdgcn_readfirstlane(tid >> 6);
  int tok0 = blockIdx.x * 64;
  float acc[10];
#pragma unroll
  for (int k = 0; k < 10; ++k) acc[k] = 0.f;

  for (int d0 = 0; d0 < Dq; d0 += 32) {
    __syncthreads();
#pragma unroll
    for (int l = 0; l < 2; ++l) {
      int idx = l * 256 + tid;
      int r = idx >> 3, c4 = idx & 7;
      float4 v = *(const float4*)(x + (size_t)(tok0 + r) * Dq + d0 + c4 * 4);
      *(float4*)(tile + r * 36 + c4 * 4) = v;
    }
    __syncthreads();
    float4 xr[8];
#pragma unroll
    for (int q = 0; q < 8; ++q) xr[q] = *(const float4*)(tile + lane * 36 + q * 4);
#pragma unroll
    for (int k = 0; k < 10; ++k) {
      int cc = wq + 4 * k;
      if (cc < Cq) {
        const float* wr = Wt + (size_t)cc * Dq + d0;
        float a = acc[k];
#pragma unroll
        for (int q = 0; q < 8; ++q) {
          a += xr[q].x * wr[q * 4 + 0];
          a += xr[q].y * wr[q * 4 + 1];
          a += xr[q].z * wr[q * 4 + 2];
          a += xr[q].w * wr[q * 4 + 3];
        }
        acc[k] = a;
      }
    }
  }
#pragma unroll
  for (int k = 0; k < 10; ++k) {
    int cc = wq + 4 * k;
    if (cc < Cq) em[(size_t)(tok0 + lane) * Cq + cc] = acc[k] + bias[cc];
  }
}

// ---------------- Kernel 2: serial CRF ----------------
__global__ __launch_bounds__(256) void crf_serial_kernel(
    const float* __restrict__ em, const float* __restrict__ startv,
    const float* __restrict__ endv, const float* __restrict__ trans,
    const int* __restrict__ labels, const unsigned char* __restrict__ maskb,
    float* __restrict__ vhist, float* __restrict__ llp,
    int* __restrict__ lenp, int* __restrict__ lastp)
{
  int b = blockIdx.x;
  int tid = threadIdx.x, wid = tid >> 6, lane = tid & 63;
  int cl = lane < Cq ? lane : Cq - 1;
  __shared__ float s_score, s_logZ;

  int esz4 = (maskb[1] == 0) ? 1 : 0;
  int len = 0;
#pragma unroll
  for (int k = 0; k < 8; ++k) {
    size_t t = (size_t)lane + (size_t)k * 64;
    unsigned char mb = esz4 ? maskb[((size_t)b * Sq + t) * 4] : maskb[(size_t)b * Sq + t];
    len += (mb != 0);
  }
#pragma unroll
  for (int off = 32; off; off >>= 1) len += __shfl_xor(len, off);

  const float* emb = em + (size_t)b * Sq * Cq;
  const float L2E = 1.4426950408889634f, LN2 = 0.6931471805599453f;

  if (wid == 0) {
    // ---- forward algorithm: E0..E36 = exp(trans[p][cl]) in named regs ----
#define DECLE(i) float E##i = __expf(trans[(i) * Cq + cl]);
    REP37(DECLE)
    float alpha = (lane < Cq) ? (startv[cl] + emb[cl]) : -3.0e38f;
    float emA = emb[1 * Cq + cl], emB = emb[2 * Cq + cl];
    float emC = emb[3 * Cq + cl], emD = emb[4 * Cq + cl];   // len>=16 guaranteed
    for (int t = 1; t < len; ++t) {
      float em_cur = emA; emA = emB; emB = emC; emC = emD;
      int tn = (t + 4 < len) ? t + 4 : len - 1;
      emD = emb[(size_t)tn * Cq + cl];
      float m = ffl(alpha);
      float e = exp2f((alpha - m) * L2E);
      float s0 = 0.f, s1 = 0.f, s2 = 0.f, s3 = 0.f;
#define FACC(i) { float ee = frl(e, (i)); \
      if (((i)&3)==0) s0 = fmaf(ee, E##i, s0); else if (((i)&3)==1) s1 = fmaf(ee, E##i, s1); \
      else if (((i)&3)==2) s2 = fmaf(ee, E##i, s2); else s3 = fmaf(ee, E##i, s3); }
      REP37(FACC)
      float ssum = (s0 + s1) + (s2 + s3);
      alpha = m + log2f(ssum) * LN2 + em_cur;
    }
    float xv = (lane < Cq) ? alpha + endv[cl] : -3.0e38f;
    float mm = xv;
#pragma unroll
    for (int off = 32; off; off >>= 1) mm = fmaxf(mm, __shfl_xor(mm, off));
    float es = exp2f((xv - mm) * L2E);
#pragma unroll
    for (int off = 32; off; off >>= 1) es += __shfl_xor(es, off);
    if (lane == 0) s_logZ = mm + log2f(es) * LN2;
  } else if (wid == 1) {
    // ---- viterbi values: T0..T36 in named regs ----
#define DECLT(i) float T##i = trans[(i) * Cq + cl];
    REP37(DECLT)
    float v = (lane < Cq) ? (startv[cl] + emb[cl]) : -3.0e38f;
    if (lane < Cq) vhist[((size_t)b * Sq) * VST + cl] = v;
    float emA = emb[1 * Cq + cl], emB = emb[2 * Cq + cl];
    float emC = emb[3 * Cq + cl], emD = emb[4 * Cq + cl];
    for (int t = 1; t < len; ++t) {
      float em_cur = emA; emA = emB; emB = emC; emC = emD;
      int tn = (t + 4 < len) ? t + 4 : len - 1;
      emD = emb[(size_t)tn * Cq + cl];
      float b0 = -3.0e38f, b1 = -3.0e38f, b2 = -3.0e38f, b3 = -3.0e38f;
#define VMAX(i) { float cnd = frl(v, (i)) + T##i; \
      if (((i)&3)==0) b0 = fmaxf(b0, cnd); else if (((i)&3)==1) b1 = fmaxf(b1, cnd); \
      else if (((i)&3)==2) b2 = fmaxf(b2, cnd); else b3 = fmaxf(b3, cnd); }
      REP37(VMAX)
      float best = fmaxf(fmaxf(b0, b1), fmaxf(b2, b3));
      v = (lane < Cq) ? best + em_cur : -3.0e38f;
      if (lane < Cq) vhist[((size_t)b * Sq + t) * VST + cl] = v;
    }
    float xv = (lane < Cq) ? v + endv[cl] : -3.0e38f;
    int idx = (lane < Cq) ? lane : 1000;
#pragma unroll
    for (int off = 32; off; off >>= 1) {
      float xo = __shfl_xor(xv, off); int io = __shfl_xor(idx, off);
      if (xo > xv || (xo == xv && io < idx)) { xv = xo; idx = io; }
    }
    if (lane == 0) { lastp[b] = idx; lenp[b] = len; }
  } else if (wid == 2) {
    // ---- gold path score ----
    const int* lab = labels + (size_t)b * Sq;
    float sc = 0.f;
#pragma unroll
    for (int k = 0; k < 8; ++k) {
      int t = 1 + lane + k * 64;
      if (t < len) {
        int lp = lab[t - 1], lt = lab[t];
        sc += trans[lp * Cq + lt] + emb[(size_t)t * Cq + lt];
      }
    }
#pragma unroll
    for (int off = 32; off; off >>= 1) sc += __shfl_xor(sc, off);
    if (lane == 0) {
      int l0 = lab[0], lf = lab[len - 1];
      s_score = sc + startv[l0] + emb[l0] + endv[lf];
    }
  }
  __syncthreads();
  if (tid == 0) llp[b] = s_score - s_logZ;
}

// ---------------- Kernel 3: backpointers (parallel recompute) ----------------
__global__ __launch_bounds__(256) void crf_bp_kernel(
    const float* __restrict__ vhist, const float* __restrict__ trans,
    const int* __restrict__ lenp, unsigned char* __restrict__ bp)
{
  int b = blockIdx.x >> 2, chunk = blockIdx.x & 3;
  int wid = threadIdx.x >> 6, lane = threadIdx.x & 63;
  int cl = lane < Cq ? lane : Cq - 1;
  int len = lenp[b];
  REP37(DECLT)                              // T0..T36 named regs (same macro)
  int tend = 1 + (chunk + 1) * 128; if (tend > len) tend = len;
  int rl9 = lane < VST ? lane : VST - 1;
  for (int t = 1 + chunk * 128 + wid; t < tend; t += 4) {
    float vr = vhist[((size_t)b * Sq + (t - 1)) * VST + rl9];
    float best = -3.0e38f; int bi = 0;
#define BARG(i) { float cnd = frl(vr, (i)) + T##i; if (cnd > best) { best = cnd; bi = (i); } }
    REP37(BARG)                             // ascending + strict '>' => first-index tie-break
    if (lane < Cq) bp[((size_t)b * VST + cl) * Sq + t] = (unsigned char)bi;
  }
}

// ---------------- Kernel 4: register-resident backtrack ----------------
__global__ __launch_bounds__(64) void crf_back_kernel(
    const unsigned char* __restrict__ bp, const int* __restrict__ lenp,
    const int* __restrict__ lastp, float* __restrict__ outp)
{
  int b = blockIdx.x, lane = threadIdx.x;
  int len = __builtin_amdgcn_readfirstlane(lenp[b]);
  int tag = __builtin_amdgcn_readfirstlane(lastp[b]);
  int row = lane < VST ? lane : VST - 1;
  const uint4* src = (const uint4*)(bp + ((size_t)b * VST + row) * Sq);
  unsigned r[128];
#pragma unroll
  for (int k = 0; k < 32; ++k) {
    uint4 q = src[k];
    r[4 * k] = q.x; r[4 * k + 1] = q.y; r[4 * k + 2] = q.z; r[4 * k + 3] = q.w;
  }
  unsigned vt[8];
#pragma unroll
  for (int j = 0; j < 8; ++j) vt[j] = 0u;
  vt[7] = (lane == 63) ? (unsigned)tag : vt[7];
#pragma unroll
  for (int t = 510; t >= 0; --t) {
    int word = __builtin_amdgcn_readlane((int)r[(t + 1) >> 2], tag);
    int nt = (word >> (((t + 1) & 3) * 8)) & 0xff;
    tag = (t + 1 < len) ? nt : tag;
    vt[t >> 6] = (lane == (t & 63)) ? (unsigned)tag : vt[t >> 6];
  }
#pragma unroll
  for (int j = 0; j < 8; ++j) {
    int t = j * 64 + lane;
    float o = (t < len) ? (float)(int)vt[j] : 36.0f;
    outp[(size_t)b * Sq + t] = o;
  }
}

// ---------------- Kernel 5: reduce ll partials ----------------
__global__ __launch_bounds__(64) void ll_reduce_kernel(
    const float* __restrict__ llp, float* __restrict__ outp)
{
  int lane = threadIdx.x;
  float s = llp[lane] + llp[lane + 64];
#pragma unroll
  for (int off = 32; off; off >>= 1) s += __shfl_xor(s, off);
  if (lane == 0) outp[0] = s;
}

extern "C" void kernel_launch(void* const* d_in, const int* in_sizes, int n_in,
                              void* d_out, int out_size, void* d_ws, size_t ws_size,
                              hipStream_t stream)
{
  const float* x      = (const float*)d_in[0];
  const float* W      = (const float*)d_in[1];
  const float* bias   = (const float*)d_in[2];
  const float* startv = (const float*)d_in[3];
  const float* endv   = (const float*)d_in[4];
  const float* trans  = (const float*)d_in[5];
  const int*   labels = (const int*)d_in[6];
  const unsigned char* maskb = (const unsigned char*)d_in[7];
  float* out = (float*)d_out;

  char* ws = (char*)d_ws;
  float* em            = (float*)(ws);
  float* vhist         = (float*)(ws + 9699328);
  unsigned char* bpbuf = (unsigned char*)(ws + 20185088);
  float* llp           = (float*)(ws + 22806528);
  int*   lenp          = (int*)(ws + 22807040);
  int*   lastp         = (int*)(ws + 22807552);
  float* Wt            = (float*)(ws + 22808064);

  prep_kernel<<<28, 256, 0, stream>>>(W, Wt);
  emis_kernel<<<1024, 256, 0, stream>>>(x, Wt, bias, em);
  crf_serial_kernel<<<128, 256, 0, stream>>>(em, startv, endv, trans, labels, maskb,
                                             vhist, llp, lenp, lastp);
  crf_bp_kernel<<<512, 256, 0, stream>>>(vhist, trans, lenp, bpbuf);
  crf_back_kernel<<<128, 64, 0, stream>>>(bpbuf, lenp, lastp, out + 1);
  ll_reduce_kernel<<<1, 64, 0, stream>>>(llp, out);
}

// Round 5
// 331.235 us; speedup vs baseline: 1.1021x; 1.1021x over previous
//
#include <hip/hip_runtime.h>

#define Bq 128
#define Sq 512
#define Cq 37
#define Dq 768
#define VST 40   // vhist row stride in floats; bp row stride uses Sq

static __device__ __forceinline__ float frl(float v, int lane) {
  return __int_as_float(__builtin_amdgcn_readlane(__float_as_int(v), lane));
}
static __device__ __forceinline__ float ffl(float v) {
  return __int_as_float(__builtin_amdgcn_readfirstlane(__float_as_int(v)));
}

#define REP37(X) X(0)X(1)X(2)X(3)X(4)X(5)X(6)X(7)X(8)X(9)X(10)X(11)X(12)X(13) \
  X(14)X(15)X(16)X(17)X(18)X(19)X(20)X(21)X(22)X(23)X(24)X(25)X(26)X(27)X(28) \
  X(29)X(30)X(31)X(32)X(33)X(34)X(35)X(36)

// ---------------- Kernel 0: transpose W -> Wt[c][d] ----------------
__global__ __launch_bounds__(256) void prep_kernel(
    const float* __restrict__ W, float* __restrict__ Wt)
{
  for (int i = blockIdx.x * 256 + threadIdx.x; i < Dq * Cq; i += gridDim.x * 256) {
    int d = i / Cq, c = i % Cq;
    Wt[(size_t)c * Dq + d] = W[i];
  }
}

// ---------------- Kernel 1: emissions = x @ W + b ----------------
__global__ __launch_bounds__(256) void emis_kernel(
    const float* __restrict__ x, const float* __restrict__ Wt,
    const float* __restrict__ bias, float* __restrict__ em)
{
  __shared__ float tile[64 * 36];
  int tid = threadIdx.x;
  int lane = tid & 63;
  int wq = __builtin_amdgcn_readfirstlane(tid >> 6);
  int tok0 = blockIdx.x * 64;
  float acc[10];
#pragma unroll
  for (int k = 0; k < 10; ++k) acc[k] = 0.f;

  for (int d0 = 0; d0 < Dq; d0 += 32) {
    __syncthreads();
#pragma unroll
    for (int l = 0; l < 2; ++l) {
      int idx = l * 256 + tid;
      int r = idx >> 3, c4 = idx & 7;
      float4 v = *(const float4*)(x + (size_t)(tok0 + r) * Dq + d0 + c4 * 4);
      *(float4*)(tile + r * 36 + c4 * 4) = v;
    }
    __syncthreads();
    float4 xr[8];
#pragma unroll
    for (int q = 0; q < 8; ++q) xr[q] = *(const float4*)(tile + lane * 36 + q * 4);
#pragma unroll
    for (int k = 0; k < 10; ++k) {
      int cc = wq + 4 * k;
      if (cc < Cq) {
        const float* wr = Wt + (size_t)cc * Dq + d0;
        float a = acc[k];
#pragma unroll
        for (int q = 0; q < 8; ++q) {
          a += xr[q].x * wr[q * 4 + 0];
          a += xr[q].y * wr[q * 4 + 1];
          a += xr[q].z * wr[q * 4 + 2];
          a += xr[q].w * wr[q * 4 + 3];
        }
        acc[k] = a;
      }
    }
  }
#pragma unroll
  for (int k = 0; k < 10; ++k) {
    int cc = wq + 4 * k;
    if (cc < Cq) em[(size_t)(tok0 + lane) * Cq + cc] = acc[k] + bias[cc];
  }
}

// ---------------- Kernel 2: serial CRF — em slice staged in LDS ----------------
__global__ __launch_bounds__(256) void crf_serial_kernel(
    const float* __restrict__ em, const float* __restrict__ startv,
    const float* __restrict__ endv, const float* __restrict__ trans,
    const int* __restrict__ labels, const unsigned char* __restrict__ maskb,
    float* __restrict__ vhist, float* __restrict__ llp,
    int* __restrict__ lenp, int* __restrict__ lastp)
{
  __shared__ float semm[Sq * Cq];          // 75,776 B: whole em[b] slice
  __shared__ float s_score, s_logZ;
  int b = blockIdx.x;
  int tid = threadIdx.x, wid = tid >> 6, lane = tid & 63;
  int cl = lane < Cq ? lane : Cq - 1;

  int esz4 = (maskb[1] == 0) ? 1 : 0;
  int len = 0;
#pragma unroll
  for (int k = 0; k < 8; ++k) {
    size_t t = (size_t)lane + (size_t)k * 64;
    unsigned char mb = esz4 ? maskb[((size_t)b * Sq + t) * 4] : maskb[(size_t)b * Sq + t];
    len += (mb != 0);
  }
#pragma unroll
  for (int off = 32; off; off >>= 1) len += __shfl_xor(len, off);

  // ---- cooperative stage: em[b] (18944 floats = 4736 float4) -> LDS ----
  const float4* src4 = (const float4*)(em + (size_t)b * Sq * Cq);
  float4* dst4 = (float4*)semm;
  for (int i = tid; i < (Sq * Cq) / 4; i += 256) dst4[i] = src4[i];
  __syncthreads();

  const float L2E = 1.4426950408889634f, LN2 = 0.6931471805599453f;

  if (wid == 0) {
    // ---- forward algorithm; all loop loads are LDS ----
#define DECLE(i) float E##i = __expf(trans[(i) * Cq + cl]);
    REP37(DECLE)
    float alpha = (lane < Cq) ? (startv[cl] + semm[cl]) : -3.0e38f;
    float emA = semm[1 * Cq + cl], emB = semm[2 * Cq + cl];
    float emC = semm[3 * Cq + cl], emD = semm[4 * Cq + cl];   // len>=16
    for (int t = 1; t < len; ++t) {
      float em_cur = emA; emA = emB; emB = emC; emC = emD;
      int tn = (t + 4 < len) ? t + 4 : len - 1;
      emD = semm[tn * Cq + cl];
      float m = ffl(alpha);
      float e = exp2f((alpha - m) * L2E);
      float s0 = 0.f, s1 = 0.f, s2 = 0.f, s3 = 0.f;
#define FACC(i) { float ee = frl(e, (i)); \
      if (((i)&3)==0) s0 = fmaf(ee, E##i, s0); else if (((i)&3)==1) s1 = fmaf(ee, E##i, s1); \
      else if (((i)&3)==2) s2 = fmaf(ee, E##i, s2); else s3 = fmaf(ee, E##i, s3); }
      REP37(FACC)
      float ssum = (s0 + s1) + (s2 + s3);
      alpha = m + log2f(ssum) * LN2 + em_cur;
    }
    float xv = (lane < Cq) ? alpha + endv[cl] : -3.0e38f;
    float mm = xv;
#pragma unroll
    for (int off = 32; off; off >>= 1) mm = fmaxf(mm, __shfl_xor(mm, off));
    float es = exp2f((xv - mm) * L2E);
#pragma unroll
    for (int off = 32; off; off >>= 1) es += __shfl_xor(es, off);
    if (lane == 0) s_logZ = mm + log2f(es) * LN2;
  } else if (wid == 1) {
    // ---- viterbi values; em from LDS, vhist stores fire-and-forget ----
#define DECLT(i) float T##i = trans[(i) * Cq + cl];
    REP37(DECLT)
    float v = (lane < Cq) ? (startv[cl] + semm[cl]) : -3.0e38f;
    if (lane < Cq) vhist[((size_t)b * Sq) * VST + cl] = v;
    float emA = semm[1 * Cq + cl], emB = semm[2 * Cq + cl];
    float emC = semm[3 * Cq + cl], emD = semm[4 * Cq + cl];
    for (int t = 1; t < len; ++t) {
      float em_cur = emA; emA = emB; emB = emC; emC = emD;
      int tn = (t + 4 < len) ? t + 4 : len - 1;
      emD = semm[tn * Cq + cl];
      float b0 = -3.0e38f, b1 = -3.0e38f, b2 = -3.0e38f, b3 = -3.0e38f;
#define VMAX(i) { float cnd = frl(v, (i)) + T##i; \
      if (((i)&3)==0) b0 = fmaxf(b0, cnd); else if (((i)&3)==1) b1 = fmaxf(b1, cnd); \
      else if (((i)&3)==2) b2 = fmaxf(b2, cnd); else b3 = fmaxf(b3, cnd); }
      REP37(VMAX)
      float best = fmaxf(fmaxf(b0, b1), fmaxf(b2, b3));
      v = (lane < Cq) ? best + em_cur : -3.0e38f;
      if (lane < Cq) vhist[((size_t)b * Sq + t) * VST + cl] = v;
    }
    float xv = (lane < Cq) ? v + endv[cl] : -3.0e38f;
    int idx = (lane < Cq) ? lane : 1000;
#pragma unroll
    for (int off = 32; off; off >>= 1) {
      float xo = __shfl_xor(xv, off); int io = __shfl_xor(idx, off);
      if (xo > xv || (xo == xv && io < idx)) { xv = xo; idx = io; }
    }
    if (lane == 0) { lastp[b] = idx; lenp[b] = len; }
  } else if (wid == 2) {
    // ---- gold path score; em from LDS ----
    const int* lab = labels + (size_t)b * Sq;
    float sc = 0.f;
#pragma unroll
    for (int k = 0; k < 8; ++k) {
      int t = 1 + lane + k * 64;
      if (t < len) {
        int lp = lab[t - 1], lt = lab[t];
        sc += trans[lp * Cq + lt] + semm[t * Cq + lt];
      }
    }
#pragma unroll
    for (int off = 32; off; off >>= 1) sc += __shfl_xor(sc, off);
    if (lane == 0) {
      int l0 = lab[0], lf = lab[len - 1];
      s_score = sc + startv[l0] + semm[l0] + endv[lf];
    }
  }
  __syncthreads();
  if (tid == 0) llp[b] = s_score - s_logZ;
}

// ---------------- Kernel 3: backpointers (parallel recompute) ----------------
__global__ __launch_bounds__(256) void crf_bp_kernel(
    const float* __restrict__ vhist, const float* __restrict__ trans,
    const int* __restrict__ lenp, unsigned char* __restrict__ bp)
{
  int b = blockIdx.x >> 2, chunk = blockIdx.x & 3;
  int wid = threadIdx.x >> 6, lane = threadIdx.x & 63;
  int cl = lane < Cq ? lane : Cq - 1;
  int len = lenp[b];
  REP37(DECLT)
  int tend = 1 + (chunk + 1) * 128; if (tend > len) tend = len;
  int rl9 = lane < VST ? lane : VST - 1;
  for (int t = 1 + chunk * 128 + wid; t < tend; t += 4) {
    float vr = vhist[((size_t)b * Sq + (t - 1)) * VST + rl9];
    float best = -3.0e38f; int bi = 0;
#define BARG(i) { float cnd = frl(vr, (i)) + T##i; if (cnd > best) { best = cnd; bi = (i); } }
    REP37(BARG)
    if (lane < Cq) bp[((size_t)b * VST + cl) * Sq + t] = (unsigned char)bi;
  }
}

// ---------------- Kernel 4: register-resident backtrack ----------------
__global__ __launch_bounds__(64) void crf_back_kernel(
    const unsigned char* __restrict__ bp, const int* __restrict__ lenp,
    const int* __restrict__ lastp, float* __restrict__ outp)
{
  int b = blockIdx.x, lane = threadIdx.x;
  int len = __builtin_amdgcn_readfirstlane(lenp[b]);
  int tag = __builtin_amdgcn_readfirstlane(lastp[b]);
  int row = lane < VST ? lane : VST - 1;
  const uint4* src = (const uint4*)(bp + ((size_t)b * VST + row) * Sq);
  unsigned r[128];
#pragma unroll
  for (int k = 0; k < 32; ++k) {
    uint4 q = src[k];
    r[4 * k] = q.x; r[4 * k + 1] = q.y; r[4 * k + 2] = q.z; r[4 * k + 3] = q.w;
  }
  unsigned vt[8];
#pragma unroll
  for (int j = 0; j < 8; ++j) vt[j] = 0u;
  vt[7] = (lane == 63) ? (unsigned)tag : vt[7];
#pragma unroll
  for (int t = 510; t >= 0; --t) {
    int word = __builtin_amdgcn_readlane((int)r[(t + 1) >> 2], tag);
    int nt = (word >> (((t + 1) & 3) * 8)) & 0xff;
    tag = (t + 1 < len) ? nt : tag;
    vt[t >> 6] = (lane == (t & 63)) ? (unsigned)tag : vt[t >> 6];
  }
#pragma unroll
  for (int j = 0; j < 8; ++j) {
    int t = j * 64 + lane;
    float o = (t < len) ? (float)(int)vt[j] : 36.0f;
    outp[(size_t)b * Sq + t] = o;
  }
}

// ---------------- Kernel 5: reduce ll partials ----------------
__global__ __launch_bounds__(64) void ll_reduce_kernel(
    const float* __restrict__ llp, float* __restrict__ outp)
{
  int lane = threadIdx.x;
  float s = llp[lane] + llp[lane + 64];
#pragma unroll
  for (int off = 32; off; off >>= 1) s += __shfl_xor(s, off);
  if (lane == 0) outp[0] = s;
}

extern "C" void kernel_launch(void* const* d_in, const int* in_sizes, int n_in,
                              void* d_out, int out_size, void* d_ws, size_t ws_size,
                              hipStream_t stream)
{
  const float* x      = (const float*)d_in[0];
  const float* W      = (const float*)d_in[1];
  const float* bias   = (const float*)d_in[2];
  const float* startv = (const float*)d_in[3];
  const float* endv   = (const float*)d_in[4];
  const float* trans  = (const float*)d_in[5];
  const int*   labels = (const int*)d_in[6];
  const unsigned char* maskb = (const unsigned char*)d_in[7];
  float* out = (float*)d_out;

  char* ws = (char*)d_ws;
  float* em            = (float*)(ws);
  float* vhist         = (float*)(ws + 9699328);
  unsigned char* bpbuf = (unsigned char*)(ws + 20185088);
  float* llp           = (float*)(ws + 22806528);
  int*   lenp          = (int*)(ws + 22807040);
  int*   lastp         = (int*)(ws + 22807552);
  float* Wt            = (float*)(ws + 22808064);

  prep_kernel<<<28, 256, 0, stream>>>(W, Wt);
  emis_kernel<<<1024, 256, 0, stream>>>(x, Wt, bias, em);
  crf_serial_kernel<<<128, 256, 0, stream>>>(em, startv, endv, trans, labels, maskb,
                                             vhist, llp, lenp, lastp);
  crf_bp_kernel<<<512, 256, 0, stream>>>(vhist, trans, lenp, bpbuf);
  crf_back_kernel<<<128, 64, 0, stream>>>(bpbuf, lenp, lastp, out + 1);
  ll_reduce_kernel<<<1, 64, 0, stream>>>(llp, out);
}

// Round 6
// 296.166 us; speedup vs baseline: 1.2326x; 1.1184x over previous
//
#include <hip/hip_runtime.h>

#define Bq 128
#define Sq 512
#define Cq 37
#define Dq 768
#define VST 40   // vhist row stride in floats; bp row stride uses Sq

// broadcast lane p's value to all lanes via ds_bpermute (VGPR result -> no
// SGPR-write hazard, unlike v_readlane which stalled ~800 cyc/step in R3-R5)
static __device__ __forceinline__ float bcast(float v, int p) {
  return __int_as_float(__builtin_amdgcn_ds_bpermute(p << 2, __float_as_int(v)));
}

#define REP37(X) X(0)X(1)X(2)X(3)X(4)X(5)X(6)X(7)X(8)X(9)X(10)X(11)X(12)X(13) \
  X(14)X(15)X(16)X(17)X(18)X(19)X(20)X(21)X(22)X(23)X(24)X(25)X(26)X(27)X(28) \
  X(29)X(30)X(31)X(32)X(33)X(34)X(35)X(36)

// ---------------- Kernel 0: transpose W -> Wt[c][d] ----------------
__global__ __launch_bounds__(256) void prep_kernel(
    const float* __restrict__ W, float* __restrict__ Wt)
{
  for (int i = blockIdx.x * 256 + threadIdx.x; i < Dq * Cq; i += gridDim.x * 256) {
    int d = i / Cq, c = i % Cq;
    Wt[(size_t)c * Dq + d] = W[i];
  }
}

// ---------------- Kernel 1: emissions = x @ W + b ----------------
__global__ __launch_bounds__(256) void emis_kernel(
    const float* __restrict__ x, const float* __restrict__ Wt,
    const float* __restrict__ bias, float* __restrict__ em)
{
  __shared__ float tile[64 * 36];
  int tid = threadIdx.x;
  int lane = tid & 63;
  int wq = __builtin_amdgcn_readfirstlane(tid >> 6);
  int tok0 = blockIdx.x * 64;
  float acc[10];
#pragma unroll
  for (int k = 0; k < 10; ++k) acc[k] = 0.f;

  for (int d0 = 0; d0 < Dq; d0 += 32) {
    __syncthreads();
#pragma unroll
    for (int l = 0; l < 2; ++l) {
      int idx = l * 256 + tid;
      int r = idx >> 3, c4 = idx & 7;
      float4 v = *(const float4*)(x + (size_t)(tok0 + r) * Dq + d0 + c4 * 4);
      *(float4*)(tile + r * 36 + c4 * 4) = v;
    }
    __syncthreads();
    float4 xr[8];
#pragma unroll
    for (int q = 0; q < 8; ++q) xr[q] = *(const float4*)(tile + lane * 36 + q * 4);
#pragma unroll
    for (int k = 0; k < 10; ++k) {
      int cc = wq + 4 * k;
      if (cc < Cq) {
        const float* wr = Wt + (size_t)cc * Dq + d0;
        float a = acc[k];
#pragma unroll
        for (int q = 0; q < 8; ++q) {
          a += xr[q].x * wr[q * 4 + 0];
          a += xr[q].y * wr[q * 4 + 1];
          a += xr[q].z * wr[q * 4 + 2];
          a += xr[q].w * wr[q * 4 + 3];
        }
        acc[k] = a;
      }
    }
  }
#pragma unroll
  for (int k = 0; k < 10; ++k) {
    int cc = wq + 4 * k;
    if (cc < Cq) em[(size_t)(tok0 + lane) * Cq + cc] = acc[k] + bias[cc];
  }
}

// ---------------- Kernel 2: serial CRF — em in LDS, bpermute broadcasts ----------------
__global__ __launch_bounds__(256) void crf_serial_kernel(
    const float* __restrict__ em, const float* __restrict__ startv,
    const float* __restrict__ endv, const float* __restrict__ trans,
    const int* __restrict__ labels, const unsigned char* __restrict__ maskb,
    float* __restrict__ vhist, float* __restrict__ llp,
    int* __restrict__ lenp, int* __restrict__ lastp)
{
  __shared__ float semm[Sq * Cq];          // 75,776 B: whole em[b] slice
  __shared__ float s_score, s_logZ;
  int b = blockIdx.x;
  int tid = threadIdx.x, wid = tid >> 6, lane = tid & 63;
  int cl = lane < Cq ? lane : Cq - 1;

  int esz4 = (maskb[1] == 0) ? 1 : 0;
  int len = 0;
#pragma unroll
  for (int k = 0; k < 8; ++k) {
    size_t t = (size_t)lane + (size_t)k * 64;
    unsigned char mb = esz4 ? maskb[((size_t)b * Sq + t) * 4] : maskb[(size_t)b * Sq + t];
    len += (mb != 0);
  }
#pragma unroll
  for (int off = 32; off; off >>= 1) len += __shfl_xor(len, off);

  // ---- cooperative stage: em[b] -> LDS ----
  const float4* src4 = (const float4*)(em + (size_t)b * Sq * Cq);
  float4* dst4 = (float4*)semm;
  for (int i = tid; i < (Sq * Cq) / 4; i += 256) dst4[i] = src4[i];
  __syncthreads();

  const float L2E = 1.4426950408889634f, LN2 = 0.6931471805599453f;

  if (wid == 0) {
    // ---- forward algorithm ----
#define DECLE(i) float E##i = __expf(trans[(i) * Cq + cl]);
    REP37(DECLE)
    float alpha = (lane < Cq) ? (startv[cl] + semm[cl]) : -3.0e38f;
    float emA = semm[1 * Cq + cl], emB = semm[2 * Cq + cl];
    float emC = semm[3 * Cq + cl], emD = semm[4 * Cq + cl];   // len>=16
    for (int t = 1; t < len; ++t) {
      float em_cur = emA; emA = emB; emB = emC; emC = emD;
      int tn = (t + 4 < len) ? t + 4 : len - 1;
      emD = semm[tn * Cq + cl];
      float m = bcast(alpha, 0);
      float e = exp2f((alpha - m) * L2E);
      // phase 1: batch all 37 broadcasts (independent, pipeline on LDS pipe)
#define BCASTF(i) float ee##i = bcast(e, (i));
      REP37(BCASTF)
      // phase 2: 4 independent fma chains
      float s0 = 0.f, s1 = 0.f, s2 = 0.f, s3 = 0.f;
#define FACC(i) { \
      if (((i)&3)==0) s0 = fmaf(ee##i, E##i, s0); else if (((i)&3)==1) s1 = fmaf(ee##i, E##i, s1); \
      else if (((i)&3)==2) s2 = fmaf(ee##i, E##i, s2); else s3 = fmaf(ee##i, E##i, s3); }
      REP37(FACC)
      float ssum = (s0 + s1) + (s2 + s3);
      alpha = m + log2f(ssum) * LN2 + em_cur;
    }
    float xv = (lane < Cq) ? alpha + endv[cl] : -3.0e38f;
    float mm = xv;
#pragma unroll
    for (int off = 32; off; off >>= 1) mm = fmaxf(mm, __shfl_xor(mm, off));
    float es = exp2f((xv - mm) * L2E);
#pragma unroll
    for (int off = 32; off; off >>= 1) es += __shfl_xor(es, off);
    if (lane == 0) s_logZ = mm + log2f(es) * LN2;
  } else if (wid == 1) {
    // ---- viterbi values (candidate values identical to reference order) ----
#define DECLT(i) float T##i = trans[(i) * Cq + cl];
    REP37(DECLT)
    float v = (lane < Cq) ? (startv[cl] + semm[cl]) : -3.0e38f;
    if (lane < Cq) vhist[((size_t)b * Sq) * VST + cl] = v;
    float emA = semm[1 * Cq + cl], emB = semm[2 * Cq + cl];
    float emC = semm[3 * Cq + cl], emD = semm[4 * Cq + cl];
    for (int t = 1; t < len; ++t) {
      float em_cur = emA; emA = emB; emB = emC; emC = emD;
      int tn = (t + 4 < len) ? t + 4 : len - 1;
      emD = semm[tn * Cq + cl];
#define BCASTV(i) float vv##i = bcast(v, (i));
      REP37(BCASTV)
      float b0 = -3.0e38f, b1 = -3.0e38f, b2 = -3.0e38f, b3 = -3.0e38f;
#define VMAX(i) { float cnd = vv##i + T##i; \
      if (((i)&3)==0) b0 = fmaxf(b0, cnd); else if (((i)&3)==1) b1 = fmaxf(b1, cnd); \
      else if (((i)&3)==2) b2 = fmaxf(b2, cnd); else b3 = fmaxf(b3, cnd); }
      REP37(VMAX)
      float best = fmaxf(fmaxf(b0, b1), fmaxf(b2, b3));
      v = (lane < Cq) ? best + em_cur : -3.0e38f;
      if (lane < Cq) vhist[((size_t)b * Sq + t) * VST + cl] = v;
    }
    float xv = (lane < Cq) ? v + endv[cl] : -3.0e38f;
    int idx = (lane < Cq) ? lane : 1000;
#pragma unroll
    for (int off = 32; off; off >>= 1) {
      float xo = __shfl_xor(xv, off); int io = __shfl_xor(idx, off);
      if (xo > xv || (xo == xv && io < idx)) { xv = xo; idx = io; }
    }
    if (lane == 0) { lastp[b] = idx; lenp[b] = len; }
  } else if (wid == 2) {
    // ---- gold path score ----
    const int* lab = labels + (size_t)b * Sq;
    float sc = 0.f;
#pragma unroll
    for (int k = 0; k < 8; ++k) {
      int t = 1 + lane + k * 64;
      if (t < len) {
        int lp = lab[t - 1], lt = lab[t];
        sc += trans[lp * Cq + lt] + semm[t * Cq + lt];
      }
    }
#pragma unroll
    for (int off = 32; off; off >>= 1) sc += __shfl_xor(sc, off);
    if (lane == 0) {
      int l0 = lab[0], lf = lab[len - 1];
      s_score = sc + startv[l0] + semm[l0] + endv[lf];
    }
  }
  __syncthreads();
  if (tid == 0) llp[b] = s_score - s_logZ;
}

// ---------------- Kernel 3: backpointers (parallel recompute) ----------------
__global__ __launch_bounds__(256) void crf_bp_kernel(
    const float* __restrict__ vhist, const float* __restrict__ trans,
    const int* __restrict__ lenp, unsigned char* __restrict__ bp)
{
  int b = blockIdx.x >> 2, chunk = blockIdx.x & 3;
  int wid = threadIdx.x >> 6, lane = threadIdx.x & 63;
  int cl = lane < Cq ? lane : Cq - 1;
  int len = lenp[b];
  REP37(DECLT)
  int tend = 1 + (chunk + 1) * 128; if (tend > len) tend = len;
  int rl9 = lane < VST ? lane : VST - 1;
  for (int t = 1 + chunk * 128 + wid; t < tend; t += 4) {
    float vr = vhist[((size_t)b * Sq + (t - 1)) * VST + rl9];
#define BCASTB(i) float br##i = bcast(vr, (i));
    REP37(BCASTB)
    float best = -3.0e38f; int bi = 0;
#define BARG(i) { float cnd = br##i + T##i; if (cnd > best) { best = cnd; bi = (i); } }
    REP37(BARG)                             // ascending + strict '>' => first-index tie-break
    if (lane < Cq) bp[((size_t)b * VST + cl) * Sq + t] = (unsigned char)bi;
  }
}

// ---------------- Kernel 4: register-resident backtrack ----------------
__global__ __launch_bounds__(64) void crf_back_kernel(
    const unsigned char* __restrict__ bp, const int* __restrict__ lenp,
    const int* __restrict__ lastp, float* __restrict__ outp)
{
  int b = blockIdx.x, lane = threadIdx.x;
  int len = __builtin_amdgcn_readfirstlane(lenp[b]);
  int tag = __builtin_amdgcn_readfirstlane(lastp[b]);
  int row = lane < VST ? lane : VST - 1;
  const uint4* src = (const uint4*)(bp + ((size_t)b * VST + row) * Sq);
  unsigned r[128];
#pragma unroll
  for (int k = 0; k < 32; ++k) {
    uint4 q = src[k];
    r[4 * k] = q.x; r[4 * k + 1] = q.y; r[4 * k + 2] = q.z; r[4 * k + 3] = q.w;
  }
  unsigned vt[8];
#pragma unroll
  for (int j = 0; j < 8; ++j) vt[j] = 0u;
  vt[7] = (lane == 63) ? (unsigned)tag : vt[7];
#pragma unroll
  for (int t = 510; t >= 0; --t) {
    int word = __builtin_amdgcn_readlane((int)r[(t + 1) >> 2], tag);
    int nt = (word >> (((t + 1) & 3) * 8)) & 0xff;
    tag = (t + 1 < len) ? nt : tag;
    vt[t >> 6] = (lane == (t & 63)) ? (unsigned)tag : vt[t >> 6];
  }
#pragma unroll
  for (int j = 0; j < 8; ++j) {
    int t = j * 64 + lane;
    float o = (t < len) ? (float)(int)vt[j] : 36.0f;
    outp[(size_t)b * Sq + t] = o;
  }
}

// ---------------- Kernel 5: reduce ll partials ----------------
__global__ __launch_bounds__(64) void ll_reduce_kernel(
    const float* __restrict__ llp, float* __restrict__ outp)
{
  int lane = threadIdx.x;
  float s = llp[lane] + llp[lane + 64];
#pragma unroll
  for (int off = 32; off; off >>= 1) s += __shfl_xor(s, off);
  if (lane == 0) outp[0] = s;
}

extern "C" void kernel_launch(void* const* d_in, const int* in_sizes, int n_in,
                              void* d_out, int out_size, void* d_ws, size_t ws_size,
                              hipStream_t stream)
{
  const float* x      = (const float*)d_in[0];
  const float* W      = (const float*)d_in[1];
  const float* bias   = (const float*)d_in[2];
  const float* startv = (const float*)d_in[3];
  const float* endv   = (const float*)d_in[4];
  const float* trans  = (const float*)d_in[5];
  const int*   labels = (const int*)d_in[6];
  const unsigned char* maskb = (const unsigned char*)d_in[7];
  float* out = (float*)d_out;

  char* ws = (char*)d_ws;
  float* em            = (float*)(ws);
  float* vhist         = (float*)(ws + 9699328);
  unsigned char* bpbuf = (unsigned char*)(ws + 20185088);
  float* llp           = (float*)(ws + 22806528);
  int*   lenp          = (int*)(ws + 22807040);
  int*   lastp         = (int*)(ws + 22807552);
  float* Wt            = (float*)(ws + 22808064);

  prep_kernel<<<28, 256, 0, stream>>>(W, Wt);
  emis_kernel<<<1024, 256, 0, stream>>>(x, Wt, bias, em);
  crf_serial_kernel<<<128, 256, 0, stream>>>(em, startv, endv, trans, labels, maskb,
                                             vhist, llp, lenp, lastp);
  crf_bp_kernel<<<512, 256, 0, stream>>>(vhist, trans, lenp, bpbuf);
  crf_back_kernel<<<128, 64, 0, stream>>>(bpbuf, lenp, lastp, out + 1);
  ll_reduce_kernel<<<1, 64, 0, stream>>>(llp, out);
}

// Round 7
// 295.556 us; speedup vs baseline: 1.2352x; 1.0021x over previous
//
#include <hip/hip_runtime.h>

#define Bq 128
#define Sq 512
#define Cq 37
#define Dq 768
#define VST 40   // vhist row stride in floats; bp row stride uses Sq

static __device__ __forceinline__ float bcast(float v, int p) {
  return __int_as_float(__builtin_amdgcn_ds_bpermute(p << 2, __float_as_int(v)));
}

#define REP37(X) X(0)X(1)X(2)X(3)X(4)X(5)X(6)X(7)X(8)X(9)X(10)X(11)X(12)X(13) \
  X(14)X(15)X(16)X(17)X(18)X(19)X(20)X(21)X(22)X(23)X(24)X(25)X(26)X(27)X(28) \
  X(29)X(30)X(31)X(32)X(33)X(34)X(35)X(36)

// ---------------- Kernel 0: transpose W -> Wt[c][d] ----------------
__global__ __launch_bounds__(256) void prep_kernel(
    const float* __restrict__ W, float* __restrict__ Wt)
{
  for (int i = blockIdx.x * 256 + threadIdx.x; i < Dq * Cq; i += gridDim.x * 256) {
    int d = i / Cq, c = i % Cq;
    Wt[(size_t)c * Dq + d] = W[i];
  }
}

// ---------------- Kernel 1: emissions = x @ W + b (unchanged this round) ----------------
__global__ __launch_bounds__(256) void emis_kernel(
    const float* __restrict__ x, const float* __restrict__ Wt,
    const float* __restrict__ bias, float* __restrict__ em)
{
  __shared__ float tile[64 * 36];
  int tid = threadIdx.x;
  int lane = tid & 63;
  int wq = __builtin_amdgcn_readfirstlane(tid >> 6);
  int tok0 = blockIdx.x * 64;
  float acc[10];
#pragma unroll
  for (int k = 0; k < 10; ++k) acc[k] = 0.f;

  for (int d0 = 0; d0 < Dq; d0 += 32) {
    __syncthreads();
#pragma unroll
    for (int l = 0; l < 2; ++l) {
      int idx = l * 256 + tid;
      int r = idx >> 3, c4 = idx & 7;
      float4 v = *(const float4*)(x + (size_t)(tok0 + r) * Dq + d0 + c4 * 4);
      *(float4*)(tile + r * 36 + c4 * 4) = v;
    }
    __syncthreads();
    float4 xr[8];
#pragma unroll
    for (int q = 0; q < 8; ++q) xr[q] = *(const float4*)(tile + lane * 36 + q * 4);
#pragma unroll
    for (int k = 0; k < 10; ++k) {
      int cc = wq + 4 * k;
      if (cc < Cq) {
        const float* wr = Wt + (size_t)cc * Dq + d0;
        float a = acc[k];
#pragma unroll
        for (int q = 0; q < 8; ++q) {
          a += xr[q].x * wr[q * 4 + 0];
          a += xr[q].y * wr[q * 4 + 1];
          a += xr[q].z * wr[q * 4 + 2];
          a += xr[q].w * wr[q * 4 + 3];
        }
        acc[k] = a;
      }
    }
  }
#pragma unroll
  for (int k = 0; k < 10; ++k) {
    int cc = wq + 4 * k;
    if (cc < Cq) em[(size_t)(tok0 + lane) * Cq + cc] = acc[k] + bias[cc];
  }
}

// ---------------- Kernel 2: serial CRF — bulk LDS exchange per step ----------------
// Per step, the 37-value all-gather is 1 ds_write_b32 + 10 ds_read_b128
// (wave-uniform addr = broadcast, conflict-free) instead of 37 bpermutes.
// Forward uses lazy rescale (alpha' = alpha - M, re-centered every 4 steps
// with one bpermute; M added back at the end).
__global__ __launch_bounds__(256) void crf_serial_kernel(
    const float* __restrict__ em, const float* __restrict__ startv,
    const float* __restrict__ endv, const float* __restrict__ trans,
    const int* __restrict__ labels, const unsigned char* __restrict__ maskb,
    float* __restrict__ vhist, float* __restrict__ llp,
    int* __restrict__ lenp, int* __restrict__ lastp)
{
  __shared__ float semm[Sq * Cq];          // 75,776 B: whole em[b] slice
  __shared__ float sexch[128];             // [0:64) fwd exchange, [64:128) vit
  __shared__ float s_score, s_logZ;
  int b = blockIdx.x;
  int tid = threadIdx.x, wid = tid >> 6, lane = tid & 63;
  int cl = lane < Cq ? lane : Cq - 1;

  int esz4 = (maskb[1] == 0) ? 1 : 0;
  int len = 0;
#pragma unroll
  for (int k = 0; k < 8; ++k) {
    size_t t = (size_t)lane + (size_t)k * 64;
    unsigned char mb = esz4 ? maskb[((size_t)b * Sq + t) * 4] : maskb[(size_t)b * Sq + t];
    len += (mb != 0);
  }
#pragma unroll
  for (int off = 32; off; off >>= 1) len += __shfl_xor(len, off);

  // ---- cooperative stage: em[b] -> LDS ----
  const float4* src4 = (const float4*)(em + (size_t)b * Sq * Cq);
  float4* dst4 = (float4*)semm;
  for (int i = tid; i < (Sq * Cq) / 4; i += 256) dst4[i] = src4[i];
  __syncthreads();

  const float L2E = 1.4426950408889634f, LN2 = 0.6931471805599453f;

  if (wid == 0) {
    // ---- forward algorithm, shifted domain ----
#define DECLE(i) float E##i = __expf(trans[(i) * Cq + cl]);
    REP37(DECLE)
    float* sE = sexch;
    float ap = (lane < Cq) ? (startv[cl] + semm[cl]) : -3.0e38f;
    float M = bcast(ap, 0);
    ap -= M;                                // lanes>=37 -> -inf, exp2 -> 0
    float emA = semm[1 * Cq + cl], emB = semm[2 * Cq + cl];
    float emC = semm[3 * Cq + cl], emD = semm[4 * Cq + cl];   // len>=16
    for (int t = 1; t < len; ++t) {
      float em_cur = emA; emA = emB; emB = emC; emC = emD;
      int tn = (t + 4 < len) ? t + 4 : len - 1;
      emD = semm[tn * Cq + cl];
      float e = exp2f(ap * L2E);
      sE[lane] = e;                          // 1 ds_write_b32
      float gs[40];                          // constant-indexed -> regs
      float4* gv = (float4*)gs;
      const float4* se4 = (const float4*)sE;
#pragma unroll
      for (int q = 0; q < 10; ++q) gv[q] = se4[q];   // 10x ds_read_b128 bcast
      float s0 = 0.f, s1 = 0.f, s2 = 0.f, s3 = 0.f;
#define FACC(i) { \
      if (((i)&3)==0) s0 = fmaf(gs[i], E##i, s0); else if (((i)&3)==1) s1 = fmaf(gs[i], E##i, s1); \
      else if (((i)&3)==2) s2 = fmaf(gs[i], E##i, s2); else s3 = fmaf(gs[i], E##i, s3); }
      REP37(FACC)
      float ssum = (s0 + s1) + (s2 + s3);
      ap = log2f(ssum) * LN2 + em_cur;
      if ((t & 3) == 0) {                    // lazy re-center, 1 bpermute / 4 steps
        float d0 = bcast(ap, 0);
        ap -= d0; M += d0;
      }
    }
    float xv = (lane < Cq) ? ap + M + endv[cl] : -3.0e38f;
    float mm = xv;
#pragma unroll
    for (int off = 32; off; off >>= 1) mm = fmaxf(mm, __shfl_xor(mm, off));
    float es = exp2f((xv - mm) * L2E);
#pragma unroll
    for (int off = 32; off; off >>= 1) es += __shfl_xor(es, off);
    if (lane == 0) s_logZ = mm + log2f(es) * LN2;
  } else if (wid == 1) {
    // ---- viterbi values (candidates in exact reference order) ----
#define DECLT(i) float T##i = trans[(i) * Cq + cl];
    REP37(DECLT)
    float* sV = sexch + 64;
    float v = (lane < Cq) ? (startv[cl] + semm[cl]) : -3.0e38f;
    if (lane < Cq) vhist[((size_t)b * Sq) * VST + cl] = v;
    float emA = semm[1 * Cq + cl], emB = semm[2 * Cq + cl];
    float emC = semm[3 * Cq + cl], emD = semm[4 * Cq + cl];
    for (int t = 1; t < len; ++t) {
      float em_cur = emA; emA = emB; emB = emC; emC = emD;
      int tn = (t + 4 < len) ? t + 4 : len - 1;
      emD = semm[tn * Cq + cl];
      sV[lane] = v;                          // 1 ds_write_b32
      float vs[40];
      float4* vv4 = (float4*)vs;
      const float4* sv4 = (const float4*)sV;
#pragma unroll
      for (int q = 0; q < 10; ++q) vv4[q] = sv4[q];  // 10x ds_read_b128 bcast
      float b0 = -3.0e38f, b1 = -3.0e38f, b2 = -3.0e38f, b3 = -3.0e38f;
#define VMAX(i) { float cnd = vs[i] + T##i; \
      if (((i)&3)==0) b0 = fmaxf(b0, cnd); else if (((i)&3)==1) b1 = fmaxf(b1, cnd); \
      else if (((i)&3)==2) b2 = fmaxf(b2, cnd); else b3 = fmaxf(b3, cnd); }
      REP37(VMAX)
      float best = fmaxf(fmaxf(b0, b1), fmaxf(b2, b3));
      v = (lane < Cq) ? best + em_cur : -3.0e38f;
      if (lane < Cq) vhist[((size_t)b * Sq + t) * VST + cl] = v;
    }
    float xv = (lane < Cq) ? v + endv[cl] : -3.0e38f;
    int idx = (lane < Cq) ? lane : 1000;
#pragma unroll
    for (int off = 32; off; off >>= 1) {
      float xo = __shfl_xor(xv, off); int io = __shfl_xor(idx, off);
      if (xo > xv || (xo == xv && io < idx)) { xv = xo; idx = io; }
    }
    if (lane == 0) { lastp[b] = idx; lenp[b] = len; }
  } else if (wid == 2) {
    // ---- gold path score ----
    const int* lab = labels + (size_t)b * Sq;
    float sc = 0.f;
#pragma unroll
    for (int k = 0; k < 8; ++k) {
      int t = 1 + lane + k * 64;
      if (t < len) {
        int lp = lab[t - 1], lt = lab[t];
        sc += trans[lp * Cq + lt] + semm[t * Cq + lt];
      }
    }
#pragma unroll
    for (int off = 32; off; off >>= 1) sc += __shfl_xor(sc, off);
    if (lane == 0) {
      int l0 = lab[0], lf = lab[len - 1];
      s_score = sc + startv[l0] + semm[l0] + endv[lf];
    }
  }
  __syncthreads();
  if (tid == 0) llp[b] = s_score - s_logZ;
}

// ---------------- Kernel 3: backpointers (parallel recompute) ----------------
__global__ __launch_bounds__(256) void crf_bp_kernel(
    const float* __restrict__ vhist, const float* __restrict__ trans,
    const int* __restrict__ lenp, unsigned char* __restrict__ bp)
{
  int b = blockIdx.x >> 2, chunk = blockIdx.x & 3;
  int wid = threadIdx.x >> 6, lane = threadIdx.x & 63;
  int cl = lane < Cq ? lane : Cq - 1;
  int len = lenp[b];
  REP37(DECLT)
  int tend = 1 + (chunk + 1) * 128; if (tend > len) tend = len;
  int rl9 = lane < VST ? lane : VST - 1;
  for (int t = 1 + chunk * 128 + wid; t < tend; t += 4) {
    float vr = vhist[((size_t)b * Sq + (t - 1)) * VST + rl9];
#define BCASTB(i) float br##i = bcast(vr, (i));
    REP37(BCASTB)
    float best = -3.0e38f; int bi = 0;
#define BARG(i) { float cnd = br##i + T##i; if (cnd > best) { best = cnd; bi = (i); } }
    REP37(BARG)                             // ascending + strict '>' => first-index tie-break
    if (lane < Cq) bp[((size_t)b * VST + cl) * Sq + t] = (unsigned char)bi;
  }
}

// ---------------- Kernel 4: register-resident backtrack ----------------
__global__ __launch_bounds__(64) void crf_back_kernel(
    const unsigned char* __restrict__ bp, const int* __restrict__ lenp,
    const int* __restrict__ lastp, float* __restrict__ outp)
{
  int b = blockIdx.x, lane = threadIdx.x;
  int len = __builtin_amdgcn_readfirstlane(lenp[b]);
  int tag = __builtin_amdgcn_readfirstlane(lastp[b]);
  int row = lane < VST ? lane : VST - 1;
  const uint4* src = (const uint4*)(bp + ((size_t)b * VST + row) * Sq);
  unsigned r[128];
#pragma unroll
  for (int k = 0; k < 32; ++k) {
    uint4 q = src[k];
    r[4 * k] = q.x; r[4 * k + 1] = q.y; r[4 * k + 2] = q.z; r[4 * k + 3] = q.w;
  }
  unsigned vt[8];
#pragma unroll
  for (int j = 0; j < 8; ++j) vt[j] = 0u;
  vt[7] = (lane == 63) ? (unsigned)tag : vt[7];
#pragma unroll
  for (int t = 510; t >= 0; --t) {
    int word = __builtin_amdgcn_readlane((int)r[(t + 1) >> 2], tag);
    int nt = (word >> (((t + 1) & 3) * 8)) & 0xff;
    tag = (t + 1 < len) ? nt : tag;
    vt[t >> 6] = (lane == (t & 63)) ? (unsigned)tag : vt[t >> 6];
  }
#pragma unroll
  for (int j = 0; j < 8; ++j) {
    int t = j * 64 + lane;
    float o = (t < len) ? (float)(int)vt[j] : 36.0f;
    outp[(size_t)b * Sq + t] = o;
  }
}

// ---------------- Kernel 5: reduce ll partials ----------------
__global__ __launch_bounds__(64) void ll_reduce_kernel(
    const float* __restrict__ llp, float* __restrict__ outp)
{
  int lane = threadIdx.x;
  float s = llp[lane] + llp[lane + 64];
#pragma unroll
  for (int off = 32; off; off >>= 1) s += __shfl_xor(s, off);
  if (lane == 0) outp[0] = s;
}

extern "C" void kernel_launch(void* const* d_in, const int* in_sizes, int n_in,
                              void* d_out, int out_size, void* d_ws, size_t ws_size,
                              hipStream_t stream)
{
  const float* x      = (const float*)d_in[0];
  const float* W      = (const float*)d_in[1];
  const float* bias   = (const float*)d_in[2];
  const float* startv = (const float*)d_in[3];
  const float* endv   = (const float*)d_in[4];
  const float* trans  = (const float*)d_in[5];
  const int*   labels = (const int*)d_in[6];
  const unsigned char* maskb = (const unsigned char*)d_in[7];
  float* out = (float*)d_out;

  char* ws = (char*)d_ws;
  float* em            = (float*)(ws);
  float* vhist         = (float*)(ws + 9699328);
  unsigned char* bpbuf = (unsigned char*)(ws + 20185088);
  float* llp           = (float*)(ws + 22806528);
  int*   lenp          = (int*)(ws + 22807040);
  int*   lastp         = (int*)(ws + 22807552);
  float* Wt            = (float*)(ws + 22808064);

  prep_kernel<<<28, 256, 0, stream>>>(W, Wt);
  emis_kernel<<<1024, 256, 0, stream>>>(x, Wt, bias, em);
  crf_serial_kernel<<<128, 256, 0, stream>>>(em, startv, endv, trans, labels, maskb,
                                             vhist, llp, lenp, lastp);
  crf_bp_kernel<<<512, 256, 0, stream>>>(vhist, trans, lenp, bpbuf);
  crf_back_kernel<<<128, 64, 0, stream>>>(bpbuf, lenp, lastp, out + 1);
  ll_reduce_kernel<<<1, 64, 0, stream>>>(llp, out);
}

// Round 8
// 289.846 us; speedup vs baseline: 1.2595x; 1.0197x over previous
//
#include <hip/hip_runtime.h>

#define Bq 128
#define Sq 512
#define Cq 37
#define Dq 768
#define VST 40   // vhist row stride in floats; bp row stride uses Sq

static __device__ __forceinline__ float bcast(float v, int p) {
  return __int_as_float(__builtin_amdgcn_ds_bpermute(p << 2, __float_as_int(v)));
}

#define REP37(X) X(0)X(1)X(2)X(3)X(4)X(5)X(6)X(7)X(8)X(9)X(10)X(11)X(12)X(13) \
  X(14)X(15)X(16)X(17)X(18)X(19)X(20)X(21)X(22)X(23)X(24)X(25)X(26)X(27)X(28) \
  X(29)X(30)X(31)X(32)X(33)X(34)X(35)X(36)

// ---------------- Kernel 0: transpose W -> Wt[c][d] ----------------
__global__ __launch_bounds__(256) void prep_kernel(
    const float* __restrict__ W, float* __restrict__ Wt)
{
  for (int i = blockIdx.x * 256 + threadIdx.x; i < Dq * Cq; i += gridDim.x * 256) {
    int d = i / Cq, c = i % Cq;
    Wt[(size_t)c * Dq + d] = W[i];
  }
}

// ---------------- Kernel 1: emissions = x @ W + b ----------------
// W-tile [37][32] staged in LDS (broadcast b128 reads); x loaded directly
// from global (8 float4/lane, row-contiguous). R7's version never scalarized
// the W reads -> ~320 vector global loads/thread/iter on the issue port.
__global__ __launch_bounds__(256) void emis_kernel(
    const float* __restrict__ x, const float* __restrict__ Wt,
    const float* __restrict__ bias, float* __restrict__ em)
{
  __shared__ float wlds[Cq * 32];                       // 4736 B
  int tid = threadIdx.x;
  int lane = tid & 63;
  int wq = __builtin_amdgcn_readfirstlane(tid >> 6);    // wave id 0..3
  int tok = blockIdx.x * 64 + lane;
  const float* xr = x + (size_t)tok * Dq;
  float acc[10];
#pragma unroll
  for (int k = 0; k < 10; ++k) acc[k] = 0.f;

  for (int d0 = 0; d0 < Dq; d0 += 32) {
    __syncthreads();                                    // protect prior tile reads
    {
      int c = tid >> 3, q = tid & 7;                    // 256 threads: c 0..31
      if (c < 32)
        *(float4*)(wlds + c * 32 + q * 4) =
            *(const float4*)(Wt + (size_t)c * Dq + d0 + q * 4);
      if (tid < 40) {                                   // c 32..36
        int c2 = 32 + (tid >> 3), q2 = tid & 7;
        *(float4*)(wlds + c2 * 32 + q2 * 4) =
            *(const float4*)(Wt + (size_t)c2 * Dq + d0 + q2 * 4);
      }
    }
    __syncthreads();
    float4 xv[8];
#pragma unroll
    for (int q = 0; q < 8; ++q) xv[q] = *(const float4*)(xr + d0 + q * 4);
#pragma unroll
    for (int k = 0; k < 10; ++k) {
      int cc = wq + 4 * k;
      if (cc < Cq) {
        const float4* wr = (const float4*)(wlds + cc * 32);  // uniform -> bcast
        float a = acc[k];
#pragma unroll
        for (int q = 0; q < 8; ++q) {
          float4 w = wr[q];
          a += xv[q].x * w.x; a += xv[q].y * w.y;
          a += xv[q].z * w.z; a += xv[q].w * w.w;
        }
        acc[k] = a;
      }
    }
  }
#pragma unroll
  for (int k = 0; k < 10; ++k) {
    int cc = wq + 4 * k;
    if (cc < Cq) em[(size_t)tok * Cq + cc] = acc[k] + bias[cc];
  }
}

// ---------------- Kernel 2: serial CRF ----------------
// Forward runs in the EXP domain: no exp2/log2 on the per-step chain.
// ez' = dot * w * 2^-e, with w = 2^(em*L2E) prefetched+pre-exp'd, e = exponent
// of exchanged ez[0] (exact pow2, integer accumulator). beta = log2(ez)+eacc.
__global__ __launch_bounds__(256) void crf_serial_kernel(
    const float* __restrict__ em, const float* __restrict__ startv,
    const float* __restrict__ endv, const float* __restrict__ trans,
    const int* __restrict__ labels, const unsigned char* __restrict__ maskb,
    float* __restrict__ vhist, float* __restrict__ llp,
    int* __restrict__ lenp, int* __restrict__ lastp)
{
  __shared__ float semm[Sq * Cq];          // 75,776 B: whole em[b] slice
  __shared__ float sexch[128];             // [0:64) fwd exchange, [64:128) vit
  __shared__ float s_score, s_logZ;
  int b = blockIdx.x;
  int tid = threadIdx.x, wid = tid >> 6, lane = tid & 63;
  int cl = lane < Cq ? lane : Cq - 1;

  int esz4 = (maskb[1] == 0) ? 1 : 0;
  int len = 0;
#pragma unroll
  for (int k = 0; k < 8; ++k) {
    size_t t = (size_t)lane + (size_t)k * 64;
    unsigned char mb = esz4 ? maskb[((size_t)b * Sq + t) * 4] : maskb[(size_t)b * Sq + t];
    len += (mb != 0);
  }
#pragma unroll
  for (int off = 32; off; off >>= 1) len += __shfl_xor(len, off);

  // ---- cooperative stage: em[b] -> LDS ----
  const float4* src4 = (const float4*)(em + (size_t)b * Sq * Cq);
  float4* dst4 = (float4*)semm;
  for (int i = tid; i < (Sq * Cq) / 4; i += 256) dst4[i] = src4[i];
  __syncthreads();

  const float L2E = 1.4426950408889634f, LN2 = 0.6931471805599453f;

  if (wid == 0) {
    // ---- forward algorithm, exp domain ----
#define DECLE(i) float E##i = exp2f(trans[(i) * Cq + cl] * L2E);
    REP37(DECLE)
    float* sE = sexch;
    float a0 = (lane < Cq) ? (startv[cl] + semm[cl]) : -3.0e38f;
    float K0 = bcast(a0, 0);
    float ez = (lane < Cq) ? exp2f((a0 - K0) * L2E) : 0.f;
    int eacc = 0;
    // prefetch pipeline of w = 2^(em*L2E), 4 steps deep (len >= 16)
    float wA = exp2f(semm[1 * Cq + cl] * L2E), wB = exp2f(semm[2 * Cq + cl] * L2E);
    float wC = exp2f(semm[3 * Cq + cl] * L2E), wD = exp2f(semm[4 * Cq + cl] * L2E);
    for (int t = 1; t < len; ++t) {
      float w_cur = wA; wA = wB; wB = wC; wC = wD;
      int tn = (t + 4 < len) ? t + 4 : len - 1;
      wD = exp2f(semm[tn * Cq + cl] * L2E);
      sE[lane] = ez;                         // 1 ds_write_b32
      float gs[40];
      float4* gv = (float4*)gs;
      const float4* se4 = (const float4*)sE;
#pragma unroll
      for (int q = 0; q < 10; ++q) gv[q] = se4[q];   // 10x ds_read_b128 bcast
      // pow2 rescale factor from exchanged ez[0] (exact, off the fma chain)
      int e0 = ((__float_as_int(gs[0]) >> 23) & 255) - 127;
      float scale = __int_as_float((127 - e0) << 23);  // 2^-e0
      float s0 = 0.f, s1 = 0.f, s2 = 0.f, s3 = 0.f;
#define FACC(i) { \
      if (((i)&3)==0) s0 = fmaf(gs[i], E##i, s0); else if (((i)&3)==1) s1 = fmaf(gs[i], E##i, s1); \
      else if (((i)&3)==2) s2 = fmaf(gs[i], E##i, s2); else s3 = fmaf(gs[i], E##i, s3); }
      REP37(FACC)
      float dot = (s0 + s1) + (s2 + s3);
      ez = dot * w_cur * scale;
      eacc += e0;
    }
    float xv = (lane < Cq) ? LN2 * (log2f(ez) + (float)eacc) + endv[cl] : -3.0e38f;
    float mm = xv;
#pragma unroll
    for (int off = 32; off; off >>= 1) mm = fmaxf(mm, __shfl_xor(mm, off));
    float es = exp2f((xv - mm) * L2E);
#pragma unroll
    for (int off = 32; off; off >>= 1) es += __shfl_xor(es, off);
    if (lane == 0) s_logZ = mm + log2f(es) * LN2;
  } else if (wid == 1) {
    // ---- viterbi values (candidates in exact reference order) ----
#define DECLT(i) float T##i = trans[(i) * Cq + cl];
    REP37(DECLT)
    float* sV = sexch + 64;
    float v = (lane < Cq) ? (startv[cl] + semm[cl]) : -3.0e38f;
    if (lane < Cq) vhist[((size_t)b * Sq) * VST + cl] = v;
    float emA = semm[1 * Cq + cl], emB = semm[2 * Cq + cl];
    float emC = semm[3 * Cq + cl], emD = semm[4 * Cq + cl];
    for (int t = 1; t < len; ++t) {
      float em_cur = emA; emA = emB; emB = emC; emC = emD;
      int tn = (t + 4 < len) ? t + 4 : len - 1;
      emD = semm[tn * Cq + cl];
      sV[lane] = v;                          // 1 ds_write_b32
      float vs[40];
      float4* vv4 = (float4*)vs;
      const float4* sv4 = (const float4*)sV;
#pragma unroll
      for (int q = 0; q < 10; ++q) vv4[q] = sv4[q];  // 10x ds_read_b128 bcast
      float b0 = -3.0e38f, b1 = -3.0e38f, b2 = -3.0e38f, b3 = -3.0e38f;
#define VMAX(i) { float cnd = vs[i] + T##i; \
      if (((i)&3)==0) b0 = fmaxf(b0, cnd); else if (((i)&3)==1) b1 = fmaxf(b1, cnd); \
      else if (((i)&3)==2) b2 = fmaxf(b2, cnd); else b3 = fmaxf(b3, cnd); }
      REP37(VMAX)
      float best = fmaxf(fmaxf(b0, b1), fmaxf(b2, b3));
      v = (lane < Cq) ? best + em_cur : -3.0e38f;
      if (lane < Cq) vhist[((size_t)b * Sq + t) * VST + cl] = v;
    }
    float xv = (lane < Cq) ? v + endv[cl] : -3.0e38f;
    int idx = (lane < Cq) ? lane : 1000;
#pragma unroll
    for (int off = 32; off; off >>= 1) {
      float xo = __shfl_xor(xv, off); int io = __shfl_xor(idx, off);
      if (xo > xv || (xo == xv && io < idx)) { xv = xo; idx = io; }
    }
    if (lane == 0) { lastp[b] = idx; lenp[b] = len; }
  } else if (wid == 2) {
    // ---- gold path score ----
    const int* lab = labels + (size_t)b * Sq;
    float sc = 0.f;
#pragma unroll
    for (int k = 0; k < 8; ++k) {
      int t = 1 + lane + k * 64;
      if (t < len) {
        int lp = lab[t - 1], lt = lab[t];
        sc += trans[lp * Cq + lt] + semm[t * Cq + lt];
      }
    }
#pragma unroll
    for (int off = 32; off; off >>= 1) sc += __shfl_xor(sc, off);
    if (lane == 0) {
      int l0 = lab[0], lf = lab[len - 1];
      s_score = sc + startv[l0] + semm[l0] + endv[lf];
    }
  }
  __syncthreads();
  if (tid == 0) llp[b] = s_score - s_logZ;
}

// ---------------- Kernel 3: backpointers (parallel recompute) ----------------
__global__ __launch_bounds__(256) void crf_bp_kernel(
    const float* __restrict__ vhist, const float* __restrict__ trans,
    const int* __restrict__ lenp, unsigned char* __restrict__ bp)
{
  int b = blockIdx.x >> 2, chunk = blockIdx.x & 3;
  int wid = threadIdx.x >> 6, lane = threadIdx.x & 63;
  int cl = lane < Cq ? lane : Cq - 1;
  int len = lenp[b];
  REP37(DECLT)
  int tend = 1 + (chunk + 1) * 128; if (tend > len) tend = len;
  int rl9 = lane < VST ? lane : VST - 1;
  for (int t = 1 + chunk * 128 + wid; t < tend; t += 4) {
    float vr = vhist[((size_t)b * Sq + (t - 1)) * VST + rl9];
#define BCASTB(i) float br##i = bcast(vr, (i));
    REP37(BCASTB)
    float best = -3.0e38f; int bi = 0;
#define BARG(i) { float cnd = br##i + T##i; if (cnd > best) { best = cnd; bi = (i); } }
    REP37(BARG)                             // ascending + strict '>' => first-index tie-break
    if (lane < Cq) bp[((size_t)b * VST + cl) * Sq + t] = (unsigned char)bi;
  }
}

// ---------------- Kernel 4: register-resident backtrack ----------------
__global__ __launch_bounds__(64) void crf_back_kernel(
    const unsigned char* __restrict__ bp, const int* __restrict__ lenp,
    const int* __restrict__ lastp, float* __restrict__ outp)
{
  int b = blockIdx.x, lane = threadIdx.x;
  int len = __builtin_amdgcn_readfirstlane(lenp[b]);
  int tag = __builtin_amdgcn_readfirstlane(lastp[b]);
  int row = lane < VST ? lane : VST - 1;
  const uint4* src = (const uint4*)(bp + ((size_t)b * VST + row) * Sq);
  unsigned r[128];
#pragma unroll
  for (int k = 0; k < 32; ++k) {
    uint4 q = src[k];
    r[4 * k] = q.x; r[4 * k + 1] = q.y; r[4 * k + 2] = q.z; r[4 * k + 3] = q.w;
  }
  unsigned vt[8];
#pragma unroll
  for (int j = 0; j < 8; ++j) vt[j] = 0u;
  vt[7] = (lane == 63) ? (unsigned)tag : vt[7];
#pragma unroll
  for (int t = 510; t >= 0; --t) {
    int word = __builtin_amdgcn_readlane((int)r[(t + 1) >> 2], tag);
    int nt = (word >> (((t + 1) & 3) * 8)) & 0xff;
    tag = (t + 1 < len) ? nt : tag;
    vt[t >> 6] = (lane == (t & 63)) ? (unsigned)tag : vt[t >> 6];
  }
#pragma unroll
  for (int j = 0; j < 8; ++j) {
    int t = j * 64 + lane;
    float o = (t < len) ? (float)(int)vt[j] : 36.0f;
    outp[(size_t)b * Sq + t] = o;
  }
}

// ---------------- Kernel 5: reduce ll partials ----------------
__global__ __launch_bounds__(64) void ll_reduce_kernel(
    const float* __restrict__ llp, float* __restrict__ outp)
{
  int lane = threadIdx.x;
  float s = llp[lane] + llp[lane + 64];
#pragma unroll
  for (int off = 32; off; off >>= 1) s += __shfl_xor(s, off);
  if (lane == 0) outp[0] = s;
}

extern "C" void kernel_launch(void* const* d_in, const int* in_sizes, int n_in,
                              void* d_out, int out_size, void* d_ws, size_t ws_size,
                              hipStream_t stream)
{
  const float* x      = (const float*)d_in[0];
  const float* W      = (const float*)d_in[1];
  const float* bias   = (const float*)d_in[2];
  const float* startv = (const float*)d_in[3];
  const float* endv   = (const float*)d_in[4];
  const float* trans  = (const float*)d_in[5];
  const int*   labels = (const int*)d_in[6];
  const unsigned char* maskb = (const unsigned char*)d_in[7];
  float* out = (float*)d_out;

  char* ws = (char*)d_ws;
  float* em            = (float*)(ws);
  float* vhist         = (float*)(ws + 9699328);
  unsigned char* bpbuf = (unsigned char*)(ws + 20185088);
  float* llp           = (float*)(ws + 22806528);
  int*   lenp          = (int*)(ws + 22807040);
  int*   lastp         = (int*)(ws + 22807552);
  float* Wt            = (float*)(ws + 22808064);

  prep_kernel<<<28, 256, 0, stream>>>(W, Wt);
  emis_kernel<<<1024, 256, 0, stream>>>(x, Wt, bias, em);
  crf_serial_kernel<<<128, 256, 0, stream>>>(em, startv, endv, trans, labels, maskb,
                                             vhist, llp, lenp, lastp);
  crf_bp_kernel<<<512, 256, 0, stream>>>(vhist, trans, lenp, bpbuf);
  crf_back_kernel<<<128, 64, 0, stream>>>(bpbuf, lenp, lastp, out + 1);
  ll_reduce_kernel<<<1, 64, 0, stream>>>(llp, out);
}